// Round 13
// baseline (1503.676 us; speedup 1.0000x reference)
//
#include <hip/hip_runtime.h>
#include <cfloat>
#include <cmath>
#include <cstdint>

#define DD 768
#define MM 256
#define NKB 200000
#define SLEN 512
#define KK 200      // 2*top_k
#define TOPK 100
#define SURV_CAP 1024
#define RESC 232
#define THRC 2.70f
#define MAXMARK 32768
#define DELTA 4e-5
#define NET 12      // e-tiles of 64

typedef __attribute__((ext_vector_type(8))) short bf16x8;
typedef __attribute__((ext_vector_type(4))) float f32x4;

__device__ __forceinline__ unsigned short f2bf_rne(float x) {
  unsigned u = __float_as_uint(x);
  unsigned r = (u + 0x7FFFu + ((u >> 16) & 1u)) >> 16;
  return (unsigned short)r;
}
__device__ __forceinline__ float bf2f(unsigned short us) {
  return __uint_as_float(((unsigned)us) << 16);
}
__device__ __forceinline__ void splitbf(float x, unsigned short& hi, unsigned short& lo) {
  hi = f2bf_rne(x);
  lo = f2bf_rne(x - bf2f(hi));
}

// ---------------- Kernel A: mention embeddings (masked mean, f64) ----------------
__global__ __launch_bounds__(256) void k_mention_emb(
    const float* __restrict__ text, const int* __restrict__ msent,
    const int* __restrict__ mstart, const int* __restrict__ mlen,
    double* __restrict__ me64) {
  int m = blockIdx.x;
  int sent = msent[m], st = mstart[m], ln = mlen[m];
  const float* base = text + (size_t)sent * SLEN * DD;
  for (int d = threadIdx.x; d < DD; d += blockDim.x) {
    double acc = 0.0;
    for (int s = st; s <= st + ln; ++s) acc += (double)base[(size_t)s * DD + d];
    me64[(size_t)m * DD + d] = acc / (double)(ln + 1);
  }
}

// ------- Kernel B1: query = me @ W_ret^T + b_ret (f64) + bf16 copy + threshold -------
__global__ __launch_bounds__(256) void k_query(
    const double* __restrict__ me64, const float* __restrict__ Wret,
    const float* __restrict__ bret, double* __restrict__ q64,
    unsigned short* __restrict__ qb16, float* __restrict__ tthr) {
  int m = blockIdx.x;
  __shared__ double sme[DD];
  __shared__ float snorm[256];
  for (int d = threadIdx.x; d < DD; d += blockDim.x) sme[d] = me64[(size_t)m * DD + d];
  __syncthreads();
  float nloc = 0.f;
  for (int e = threadIdx.x; e < DD; e += blockDim.x) {
    double acc = (double)bret[e];
    const float* wr = Wret + (size_t)e * DD;
    for (int d = 0; d < DD; ++d) acc += sme[d] * (double)wr[d];
    q64[(size_t)m * DD + e] = acc;
    qb16[(size_t)m * DD + e] = f2bf_rne((float)acc);
    nloc += (float)(acc * acc);
  }
  snorm[threadIdx.x] = nloc; __syncthreads();
  for (int s = 128; s > 0; s >>= 1) {
    if (threadIdx.x < s) snorm[threadIdx.x] += snorm[threadIdx.x + s];
    __syncthreads();
  }
  if (threadIdx.x == 0) tthr[m] = THRC * sqrtf(snorm[0]);
}

// ---------------- Kernel B2: m_part = me @ Ws1[:D] (f64 + f32 copy) ----------------
__global__ __launch_bounds__(256) void k_mpart(
    const double* __restrict__ me64, const float* __restrict__ Ws1,
    double* __restrict__ mp64, float* __restrict__ mp32) {
  int m = blockIdx.x;
  __shared__ double sme[DD];
  for (int d = threadIdx.x; d < DD; d += blockDim.x) sme[d] = me64[(size_t)m * DD + d];
  __syncthreads();
  for (int e = threadIdx.x; e < DD; e += blockDim.x) {
    double acc = 0.0;
    for (int d = 0; d < DD; ++d) acc += sme[d] * (double)Ws1[(size_t)d * DD + e];
    mp64[(size_t)m * DD + e] = acc;
    mp32[(size_t)m * DD + e] = (float)acc;
  }
}

// ---------------- Kernel P: split+transpose Ws1[D:] -> Bt_hi/Bt_lo [e][k] bf16 ----------------
__global__ __launch_bounds__(256) void k_prep(
    const float* __restrict__ Ws1, unsigned short* __restrict__ Bth,
    unsigned short* __restrict__ Btl) {
  int e = blockIdx.x;
  for (int k = threadIdx.x; k < DD; k += 256) {
    float x = Ws1[(size_t)(DD + k) * DD + e];
    unsigned short hi, lo;
    splitbf(x, hi, lo);
    Bth[(size_t)e * DD + k] = hi;
    Btl[(size_t)e * DD + k] = lo;
  }
}

// ------- Kernel C: sims = q @ kb^T via bf16 MFMA; threshold-compact survivors -------
// v3: 512 thr (8 waves, wave tile 32m x 64n). A-frags direct global->reg (q is L2-hot);
// B LDS-staged with 1-step register prefetch (named double-buffer). Bit-identical math.
__global__ __launch_bounds__(512) void k_sims_mfma(
    const unsigned short* __restrict__ qb, const float* __restrict__ kb,
    const float* __restrict__ tthr, int* __restrict__ gcnt,
    uint2* __restrict__ gcand) {
  __shared__ unsigned short Bs[64 * 32];   // 4 KB, swizzled
  __shared__ float sthr[256];
  int n0 = blockIdx.x * 64;
  int tid = threadIdx.x;
  int lane = tid & 63, w = tid >> 6;       // 8 waves
  int h = lane >> 4, c = lane & 15;
  if (tid < 256) sthr[tid] = tthr[tid];
  f32x4 acc[2][4] = {};
  const int brow = n0 + (tid >> 3);        // stage row (64 rows x 8 thr/row)
  const int bk4  = (tid & 7) * 4;          // 4 f32 per thread
  const int bwoff = ((tid >> 3) * 64 + (tid & 7) * 8) ^ (((tid >> 3) & 7) << 4);
  auto ldB = [&](int k0, float4 &dst) {
    dst = *(const float4*)(kb + (size_t)brow * DD + k0 + bk4);
  };
  auto stB = [&](const float4 &v) {
    uint2 p;
    p.x = (unsigned)f2bf_rne(v.x) | ((unsigned)f2bf_rne(v.y) << 16);
    p.y = (unsigned)f2bf_rne(v.z) | ((unsigned)f2bf_rne(v.w) << 16);
    *(uint2*)((char*)Bs + bwoff) = p;
  };
  const unsigned short* qa0 = qb + (size_t)(w * 32 + c) * DD;
  const unsigned short* qa1 = qb + (size_t)(w * 32 + 16 + c) * DD;
  auto step = [&](int k0, float4 &cur, float4 &nxt, bool pf) {
    bf16x8 a0 = *(const bf16x8*)(qa0 + k0 + h * 8);   // issue early (L2-hot)
    bf16x8 a1 = *(const bf16x8*)(qa1 + k0 + h * 8);
    __syncthreads();                 // prev MFMA done reading Bs
    stB(cur);
    if (pf) ldB(k0 + 32, nxt);       // prefetch next B under this step's MFMAs
    __syncthreads();                 // Bs ready
#pragma unroll
    for (int nf = 0; nf < 4; ++nf) {
      int n = nf * 16 + c;
      int off = (n * 64 + h * 16) ^ ((n & 7) << 4);
      bf16x8 b = *(bf16x8*)((char*)Bs + off);
      acc[0][nf] = __builtin_amdgcn_mfma_f32_16x16x32_bf16(a0, b, acc[0][nf], 0, 0, 0);
      acc[1][nf] = __builtin_amdgcn_mfma_f32_16x16x32_bf16(a1, b, acc[1][nf], 0, 0, 0);
    }
  };
  float4 b0, b1;
  ldB(0, b0);
#pragma unroll
  for (int kc = 0; kc < 12; ++kc) {
    step(kc * 64,      b0, b1, true);
    step(kc * 64 + 32, b1, b0, kc < 11);
  }
  // epilogue: C[row][col]: col = lane&15, row = (lane>>4)*4 + reg
#pragma unroll
  for (int mf = 0; mf < 2; ++mf)
#pragma unroll
    for (int nf = 0; nf < 4; ++nf)
#pragma unroll
      for (int r = 0; r < 4; ++r) {
        int row = w * 32 + mf * 16 + h * 4 + r;
        int col = n0 + nf * 16 + c;
        float v = acc[mf][nf][r];
        if (v > sthr[row]) {
          int p = atomicAdd(&gcnt[row], 1);
          if (p < SURV_CAP) gcand[(size_t)row * SURV_CAP + p] = make_uint2(__float_as_uint(v), (unsigned)col);
        }
      }
}

// ------- Kernel D: per-mention select top-200: sort survivors by f32 sims,
//         f64-rescore top RESC, exact sort, emit in sims-desc order -------
__global__ __launch_bounds__(256) void k_select(
    const uint2* __restrict__ gcand, const int* __restrict__ gcnt,
    const float* __restrict__ kb, const double* __restrict__ q64,
    int* __restrict__ cidx) {
  int m = blockIdx.x;
  __shared__ float skf[SURV_CAP];
  __shared__ int   sidx[SURV_CAP];
  __shared__ double sq[DD];
  __shared__ double skey[256];
  __shared__ int    skidx[256];
  int tid = threadIdx.x;
  int cnt = gcnt[m]; if (cnt > SURV_CAP) cnt = SURV_CAP;
  for (int d = tid; d < DD; d += 256) sq[d] = q64[(size_t)m * DD + d];
  for (int i = tid; i < SURV_CAP; i += 256) {
    if (i < cnt) {
      uint2 v = gcand[(size_t)m * SURV_CAP + i];
      skf[i] = __uint_as_float(v.x);
      sidx[i] = (int)v.y;
    } else { skf[i] = -FLT_MAX; sidx[i] = 0x7fffffff; }
  }
  __syncthreads();
  // bitonic sort 1024 desc by skf, tie -> smaller idx
  for (int k = 2; k <= SURV_CAP; k <<= 1) {
    for (int j = k >> 1; j > 0; j >>= 1) {
      for (int i = tid; i < SURV_CAP; i += 256) {
        int l = i ^ j;
        if (l > i) {
          float ka = skf[i], kb2 = skf[l];
          int ia = sidx[i], ib = sidx[l];
          bool lBefore = (kb2 > ka) || (kb2 == ka && ib < ia);
          bool iBefore = (ka > kb2) || (ka == kb2 && ia < ib);
          bool dir = ((i & k) == 0);
          bool sw = dir ? lBefore : iBefore;
          if (sw) { skf[i] = kb2; skf[l] = ka; sidx[i] = ib; sidx[l] = ia; }
        }
      }
      __syncthreads();
    }
  }
  // f64 rescore top RESC (one wave per candidate)
  int lane = tid & 63, wv = tid >> 6;
  for (int cpos = wv; cpos < RESC; cpos += 4) {
    int ci = sidx[cpos];
    double s;
    if (ci < NKB) {
      const float* krow = kb + (size_t)ci * DD;
      double acc = 0.0;
      for (int d = lane; d < DD; d += 64) acc += sq[d] * (double)krow[d];
      for (int off2 = 32; off2 > 0; off2 >>= 1) acc += __shfl_down(acc, off2, 64);
      s = acc;
    } else s = -INFINITY;
    if (lane == 0) { skey[cpos] = s; skidx[cpos] = ci; }
  }
  if (tid >= RESC && tid < 256) { skey[tid] = -INFINITY; skidx[tid] = 0x7fffffff; }
  __syncthreads();
  // bitonic sort 256 desc by f64 key, tie -> smaller idx
  for (int k = 2; k <= 256; k <<= 1) {
    for (int j = k >> 1; j > 0; j >>= 1) {
      int i = tid, l = i ^ j;
      if (l > i) {
        double ka = skey[i], kb2 = skey[l];
        int ia = skidx[i], ib = skidx[l];
        bool lBefore = (kb2 > ka) || (kb2 == ka && ib < ia);
        bool iBefore = (ka > kb2) || (ka == kb2 && ia < ib);
        bool dir = ((i & k) == 0);
        bool sw = dir ? lBefore : iBefore;
        if (sw) { skey[i] = kb2; skey[l] = ka; skidx[i] = ib; skidx[l] = ia; }
      }
      __syncthreads();
    }
  }
  for (int cc = tid; cc < KK; cc += 256) {
    int v = skidx[cc];
    cidx[(size_t)m * KK + cc] = (v < NKB) ? v : 0;
  }
}

// ------- Kernel E v3: scorer GEMM partials — direct global->reg operands, ZERO barriers
// in the k-loop. 256 thr (4 waves), block = 256 cand rows x 64 e cols, K=768.
// Every MFMA operand element is consumed by exactly one lane, and both streams are
// L2-hot (A: 12 e-blocks/XCD share cand rows; B: split-Ws1 4.7 MB shared by all blocks),
// so LDS staging was pure overhead. MFMA order per acc unchanged -> bit-identical z.
__global__ __launch_bounds__(256) void k_score2(
    const float* __restrict__ kb, const int* __restrict__ cidx,
    const float* __restrict__ mp32, const unsigned short* __restrict__ Bth,
    const unsigned short* __restrict__ Btl, const float* __restrict__ bs1,
    const float* __restrict__ Ws2, float* __restrict__ gpart) {
  __shared__ float smp[3][64], sb1v[64], sw2v[64];
  __shared__ int srow[256];
  int p = blockIdx.x;
  int x = p & 7, j = p >> 3;
  int ct = x + 8 * (j / NET), et = j % NET;
  int r0 = ct * 256, e0 = et * 64;
  int tid = threadIdx.x, lane = tid & 63, w = tid >> 6;
  int h = lane >> 4, c = lane & 15;
  srow[tid] = cidx[r0 + tid];
  int m0 = r0 / KK;
  int mm1 = (m0 + 1 < MM) ? m0 + 1 : MM - 1;
  int mm2 = (m0 + 2 < MM) ? m0 + 2 : MM - 1;
  if (tid < 64) {
    smp[0][tid] = mp32[(size_t)m0 * DD + e0 + tid];
    smp[1][tid] = mp32[(size_t)mm1 * DD + e0 + tid];
    smp[2][tid] = mp32[(size_t)mm2 * DD + e0 + tid];
    sb1v[tid] = bs1[e0 + tid];
    sw2v[tid] = Ws2[e0 + tid];
  }
  __syncthreads();   // only barrier: srow + epilogue tables staged
  // per-lane operand pointers: A rows (4 mf, scattered), B cols (stride 16*DD from base)
  const float* arow[4];
#pragma unroll
  for (int mf = 0; mf < 4; ++mf)
    arow[mf] = kb + (size_t)srow[w * 64 + mf * 16 + c] * DD + h * 8;
  const unsigned short* bthb = Bth + (size_t)(e0 + c) * DD + h * 8;
  const unsigned short* btlb = Btl + (size_t)(e0 + c) * DD + h * 8;
  f32x4 acc[4][4] = {};
  for (int k0 = 0; k0 < DD; k0 += 32) {
    // A: load+split once per step (reused across nf)
    bf16x8 ah[4], al[4];
#pragma unroll
    for (int mf = 0; mf < 4; ++mf) {
      float4 v0 = *(const float4*)(arow[mf] + k0);
      float4 v1 = *(const float4*)(arow[mf] + k0 + 4);
      unsigned short hh0, hh1, hh2, hh3, hh4, hh5, hh6, hh7;
      unsigned short ll0, ll1, ll2, ll3, ll4, ll5, ll6, ll7;
      splitbf(v0.x, hh0, ll0); splitbf(v0.y, hh1, ll1);
      splitbf(v0.z, hh2, ll2); splitbf(v0.w, hh3, ll3);
      splitbf(v1.x, hh4, ll4); splitbf(v1.y, hh5, ll5);
      splitbf(v1.z, hh6, ll6); splitbf(v1.w, hh7, ll7);
      bf16x8 ah_ = {(short)hh0, (short)hh1, (short)hh2, (short)hh3,
                    (short)hh4, (short)hh5, (short)hh6, (short)hh7};
      bf16x8 al_ = {(short)ll0, (short)ll1, (short)ll2, (short)ll3,
                    (short)ll4, (short)ll5, (short)ll6, (short)ll7};
      ah[mf] = ah_;
      al[mf] = al_;
    }
    // B: per nf (same nf-outer / mf-inner order as before -> identical acc sequence)
#pragma unroll
    for (int nf = 0; nf < 4; ++nf) {
      bf16x8 bh = *(const bf16x8*)(bthb + (size_t)nf * (16 * DD) + k0);
      bf16x8 bl = *(const bf16x8*)(btlb + (size_t)nf * (16 * DD) + k0);
#pragma unroll
      for (int mf = 0; mf < 4; ++mf) {
        acc[mf][nf] = __builtin_amdgcn_mfma_f32_16x16x32_bf16(ah[mf], bh, acc[mf][nf], 0, 0, 0);
        acc[mf][nf] = __builtin_amdgcn_mfma_f32_16x16x32_bf16(ah[mf], bl, acc[mf][nf], 0, 0, 0);
        acc[mf][nf] = __builtin_amdgcn_mfma_f32_16x16x32_bf16(al[mf], bh, acc[mf][nf], 0, 0, 0);
      }
    }
  }
  // epilogue: partial z over this 64-e tile; C/D: col=c -> e, row=h*4+r -> cand row
  int bnd1 = (m0 + 1) * KK, bnd2 = (m0 + 2) * KK;
#pragma unroll
  for (int mf = 0; mf < 4; ++mf) {
    float zp[4] = {0.f, 0.f, 0.f, 0.f};
#pragma unroll
    for (int nf = 0; nf < 4; ++nf) {
      int el = nf * 16 + c;
      float b1v = sb1v[el], w2v = sw2v[el];
#pragma unroll
      for (int r = 0; r < 4; ++r) {
        int rowg = r0 + w * 64 + mf * 16 + h * 4 + r;
        int sel = (rowg >= bnd1) + (rowg >= bnd2);
        float hh = acc[mf][nf][r] + smp[sel][el] + b1v;
        if (hh > 0.f) zp[r] += hh * w2v;
      }
    }
#pragma unroll
    for (int r = 0; r < 4; ++r) {
      float v = zp[r];
      v += __shfl_xor(v, 1, 64);
      v += __shfl_xor(v, 2, 64);
      v += __shfl_xor(v, 4, 64);
      v += __shfl_xor(v, 8, 64);
      if (c == 0)
        gpart[(size_t)(r0 + w * 64 + mf * 16 + h * 4 + r) * NET + et] = v;
    }
  }
}

// ------- Kernel E1b: z64[row] = f64 sum of 12 partials + bs2 (fixed order, deterministic) -------
__global__ __launch_bounds__(256) void k_zred(
    const float* __restrict__ gpart, const float* __restrict__ bs2,
    double* __restrict__ z64) {
  int r = blockIdx.x * 256 + threadIdx.x;
  double s = 0.0;
#pragma unroll
  for (int i = 0; i < NET; ++i) s += (double)gpart[(size_t)r * NET + i];
  z64[r] = s + (double)bs2[0];
}

// ------- Kernel E2: mark ambiguous ranks (any adjacent gap < DELTA), deduped -------
__global__ __launch_bounds__(256) void k_mark(
    const double* __restrict__ z64, int* __restrict__ marks, int* __restrict__ mcnt) {
  int m = blockIdx.x;
  __shared__ double sk[256];
  __shared__ int sp[256];
  __shared__ int flag[256];
  int tid = threadIdx.x;
  flag[tid] = 0;
  if (tid < KK) { sk[tid] = z64[(size_t)m * KK + tid]; sp[tid] = tid; }
  else { sk[tid] = -INFINITY; sp[tid] = 0x7fffffff; }
  __syncthreads();
  for (int k = 2; k <= 256; k <<= 1) {
    for (int j = k >> 1; j > 0; j >>= 1) {
      int i = tid, l = i ^ j;
      if (l > i) {
        double ka = sk[i], kb2 = sk[l];
        int ia = sp[i], ib = sp[l];
        bool lBefore = (kb2 > ka) || (kb2 == ka && ib < ia);
        bool iBefore = (ka > kb2) || (ka == kb2 && ia < ib);
        bool dir = ((i & k) == 0);
        bool sw = dir ? lBefore : iBefore;
        if (sw) { sk[i] = kb2; sk[l] = ka; sp[i] = ib; sp[l] = ia; }
      }
      __syncthreads();
    }
  }
  // mark rank positions involved in any close adjacent pair within ranks 0..121
  if (tid <= 120) {
    if (sk[tid] - sk[tid + 1] < DELTA) {
      flag[tid] = 1;
      atomicExch(&flag[tid + 1], 1);
    }
  }
  __syncthreads();
  if (tid <= 121 && flag[tid]) {
    int p = atomicAdd(mcnt, 1);
    if (p < MAXMARK) marks[p] = m * KK + sp[tid];
  }
}

// ------- Kernel E3: exact f64 rescore of marked candidates (in-place into z64) -------
__global__ __launch_bounds__(256) void k_rescore(
    const float* __restrict__ kb, const int* __restrict__ cidx,
    const double* __restrict__ mp64, const float* __restrict__ Ws1,
    const float* __restrict__ bs1, const float* __restrict__ Ws2,
    const float* __restrict__ bs2, const int* __restrict__ marks,
    const int* __restrict__ mcnt, double* __restrict__ z64) {
  int cnt = *mcnt; if (cnt > MAXMARK) cnt = MAXMARK;
  __shared__ float sc[DD];
  __shared__ double sred[256];
  int tid = threadIdx.x;
  for (int it = blockIdx.x; it < cnt; it += gridDim.x) {
    int r = marks[it];
    int m = r / KK;
    int row = cidx[r];
    for (int d = tid; d < DD; d += 256) sc[d] = kb[(size_t)row * DD + d];
    __syncthreads();
    double pz = 0.0;
    for (int e = tid; e < DD; e += 256) {
      double a = 0.0;
      for (int d = 0; d < DD; ++d) a += (double)sc[d] * (double)Ws1[(size_t)(DD + d) * DD + e];
      double hv = mp64[(size_t)m * DD + e] + a + (double)bs1[e];
      if (hv > 0) pz += hv * (double)Ws2[e];
    }
    sred[tid] = pz; __syncthreads();
    for (int s = 128; s > 0; s >>= 1) { if (tid < s) sred[tid] += sred[tid + s]; __syncthreads(); }
    if (tid == 0) z64[r] = sred[0] + (double)bs2[0];
    __syncthreads();
  }
}

// ---------------- Kernel F: per-mention top-100 of 200 (bitonic 256) ----------------
__global__ __launch_bounds__(256) void k_final(
    const double* __restrict__ z64, const int* __restrict__ cidx, float* __restrict__ out) {
  int m = blockIdx.x;
  __shared__ double sk[256];
  __shared__ int sp[256];
  int tid = threadIdx.x;
  if (tid < KK) { sk[tid] = z64[(size_t)m * KK + tid]; sp[tid] = tid; }
  else { sk[tid] = -INFINITY; sp[tid] = 0x7fffffff; }
  __syncthreads();
  for (int k = 2; k <= 256; k <<= 1) {
    for (int j = k >> 1; j > 0; j >>= 1) {
      int i = tid, l = i ^ j;
      if (l > i) {
        double ka = sk[i], kb2 = sk[l];
        int ia = sp[i], ib = sp[l];
        bool lBefore = (kb2 > ka) || (kb2 == ka && ib < ia);
        bool iBefore = (ka > kb2) || (ka == kb2 && ia < ib);
        bool dir = ((i & k) == 0);
        bool sw = dir ? lBefore : iBefore;
        if (sw) { sk[i] = kb2; sk[l] = ka; sp[i] = ib; sp[l] = ia; }
      }
      __syncthreads();
    }
  }
  if (tid < TOPK) {
    double z = sk[tid];
    out[(size_t)m * TOPK + tid] = (float)(1.0 / (1.0 + exp(-z)));
    out[(size_t)MM * TOPK + (size_t)m * TOPK + tid] = (float)cidx[(size_t)m * KK + sp[tid]];
  }
}

// ---------------- host ----------------
extern "C" void kernel_launch(void* const* d_in, const int* in_sizes, int n_in,
                              void* d_out, int out_size, void* d_ws, size_t ws_size,
                              hipStream_t stream) {
  const float* text  = (const float*)d_in[0];
  const float* kb    = (const float*)d_in[1];
  const float* Wret  = (const float*)d_in[2];
  const float* bret  = (const float*)d_in[3];
  const float* Ws1   = (const float*)d_in[4];
  const float* bs1   = (const float*)d_in[5];
  const float* Ws2   = (const float*)d_in[6];
  const float* bs2   = (const float*)d_in[7];
  const int* msent   = (const int*)d_in[8];
  const int* mstart  = (const int*)d_in[9];
  const int* mlen    = (const int*)d_in[10];
  float* out = (float*)d_out;

  char* ws = (char*)d_ws;
  size_t off = 0;
  auto alloc = [&](size_t bytes) -> void* {
    void* p = ws + off;
    off = (off + bytes + 255) & ~(size_t)255;
    return p;
  };
  double* me64 = (double*)alloc((size_t)MM * DD * 8);
  double* q64  = (double*)alloc((size_t)MM * DD * 8);
  unsigned short* qb16 = (unsigned short*)alloc((size_t)MM * DD * 2);
  float*  tthr = (float*) alloc((size_t)MM * 4);
  double* mp64 = (double*)alloc((size_t)MM * DD * 8);
  float*  mp32 = (float*) alloc((size_t)MM * DD * 4);
  int*    cidx = (int*)   alloc((size_t)MM * KK * 4);
  double* z64  = (double*)alloc((size_t)MM * KK * 8);
  float*  gpart = (float*)alloc((size_t)MM * KK * NET * 4);
  int*    marks = (int*)  alloc((size_t)MAXMARK * 4);
  int*    mcnt  = (int*)  alloc(256);
  int*    gcnt  = (int*)  alloc((size_t)MM * 4);
  uint2*  gcand = (uint2*)alloc((size_t)MM * SURV_CAP * 8);
  unsigned short* Bth = (unsigned short*)alloc((size_t)DD * DD * 2);
  unsigned short* Btl = (unsigned short*)alloc((size_t)DD * DD * 2);
  (void)ws_size;

  k_mention_emb<<<MM, 256, 0, stream>>>(text, msent, mstart, mlen, me64);
  k_query<<<MM, 256, 0, stream>>>(me64, Wret, bret, q64, qb16, tthr);
  k_mpart<<<MM, 256, 0, stream>>>(me64, Ws1, mp64, mp32);
  k_prep<<<DD, 256, 0, stream>>>(Ws1, Bth, Btl);

  hipMemsetAsync(gcnt, 0, (size_t)MM * 4, stream);
  k_sims_mfma<<<NKB / 64, 512, 0, stream>>>(qb16, kb, tthr, gcnt, gcand);
  k_select<<<MM, 256, 0, stream>>>(gcand, gcnt, kb, q64, cidx);

  k_score2<<<(MM * KK / 256) * NET, 256, 0, stream>>>(kb, cidx, mp32, Bth, Btl, bs1, Ws2, gpart);
  k_zred<<<MM * KK / 256, 256, 0, stream>>>(gpart, bs2, z64);
  hipMemsetAsync(mcnt, 0, 4, stream);
  k_mark<<<MM, 256, 0, stream>>>(z64, marks, mcnt);
  k_rescore<<<2048, 256, 0, stream>>>(kb, cidx, mp64, Ws1, bs1, Ws2, bs2, marks, mcnt, z64);
  k_final<<<MM, 256, 0, stream>>>(z64, cidx, out);
}

// Round 14
// 1336.259 us; speedup vs baseline: 1.1253x; 1.1253x over previous
//
#include <hip/hip_runtime.h>
#include <cfloat>
#include <cmath>
#include <cstdint>

#define DD 768
#define MM 256
#define NKB 200000
#define SLEN 512
#define KK 200      // 2*top_k
#define TOPK 100
#define SURV_CAP 1024
#define RESC 232
#define THRC 2.70f
#define MAXMARK 32768
#define DELTA 4e-5
#define NET 12      // e-tiles of 64

typedef __attribute__((ext_vector_type(8))) short bf16x8;
typedef __attribute__((ext_vector_type(4))) float f32x4;

__device__ __forceinline__ unsigned short f2bf_rne(float x) {
  unsigned u = __float_as_uint(x);
  unsigned r = (u + 0x7FFFu + ((u >> 16) & 1u)) >> 16;
  return (unsigned short)r;
}
__device__ __forceinline__ float bf2f(unsigned short us) {
  return __uint_as_float(((unsigned)us) << 16);
}
__device__ __forceinline__ void splitbf(float x, unsigned short& hi, unsigned short& lo) {
  hi = f2bf_rne(x);
  lo = f2bf_rne(x - bf2f(hi));
}

// ---------------- Kernel A: mention embeddings (masked mean, f64) ----------------
__global__ __launch_bounds__(256) void k_mention_emb(
    const float* __restrict__ text, const int* __restrict__ msent,
    const int* __restrict__ mstart, const int* __restrict__ mlen,
    double* __restrict__ me64) {
  int m = blockIdx.x;
  int sent = msent[m], st = mstart[m], ln = mlen[m];
  const float* base = text + (size_t)sent * SLEN * DD;
  for (int d = threadIdx.x; d < DD; d += blockDim.x) {
    double acc = 0.0;
    for (int s = st; s <= st + ln; ++s) acc += (double)base[(size_t)s * DD + d];
    me64[(size_t)m * DD + d] = acc / (double)(ln + 1);
  }
}

// ------- Kernel B1: query = me @ W_ret^T + b_ret (f64) + bf16 copy + threshold -------
__global__ __launch_bounds__(256) void k_query(
    const double* __restrict__ me64, const float* __restrict__ Wret,
    const float* __restrict__ bret, double* __restrict__ q64,
    unsigned short* __restrict__ qb16, float* __restrict__ tthr) {
  int m = blockIdx.x;
  __shared__ double sme[DD];
  __shared__ float snorm[256];
  for (int d = threadIdx.x; d < DD; d += blockDim.x) sme[d] = me64[(size_t)m * DD + d];
  __syncthreads();
  float nloc = 0.f;
  for (int e = threadIdx.x; e < DD; e += blockDim.x) {
    double acc = (double)bret[e];
    const float* wr = Wret + (size_t)e * DD;
    for (int d = 0; d < DD; ++d) acc += sme[d] * (double)wr[d];
    q64[(size_t)m * DD + e] = acc;
    qb16[(size_t)m * DD + e] = f2bf_rne((float)acc);
    nloc += (float)(acc * acc);
  }
  snorm[threadIdx.x] = nloc; __syncthreads();
  for (int s = 128; s > 0; s >>= 1) {
    if (threadIdx.x < s) snorm[threadIdx.x] += snorm[threadIdx.x + s];
    __syncthreads();
  }
  if (threadIdx.x == 0) tthr[m] = THRC * sqrtf(snorm[0]);
}

// ---------------- Kernel B2: m_part = me @ Ws1[:D] (f64 + f32 copy) ----------------
__global__ __launch_bounds__(256) void k_mpart(
    const double* __restrict__ me64, const float* __restrict__ Ws1,
    double* __restrict__ mp64, float* __restrict__ mp32) {
  int m = blockIdx.x;
  __shared__ double sme[DD];
  for (int d = threadIdx.x; d < DD; d += blockDim.x) sme[d] = me64[(size_t)m * DD + d];
  __syncthreads();
  for (int e = threadIdx.x; e < DD; e += blockDim.x) {
    double acc = 0.0;
    for (int d = 0; d < DD; ++d) acc += sme[d] * (double)Ws1[(size_t)d * DD + e];
    mp64[(size_t)m * DD + e] = acc;
    mp32[(size_t)m * DD + e] = (float)acc;
  }
}

// ---------------- Kernel P: split+transpose Ws1[D:] -> Bt_hi/Bt_lo [e][k] bf16 ----------------
__global__ __launch_bounds__(256) void k_prep(
    const float* __restrict__ Ws1, unsigned short* __restrict__ Bth,
    unsigned short* __restrict__ Btl) {
  int e = blockIdx.x;
  for (int k = threadIdx.x; k < DD; k += 256) {
    float x = Ws1[(size_t)(DD + k) * DD + e];
    unsigned short hi, lo;
    splitbf(x, hi, lo);
    Bth[(size_t)e * DD + k] = hi;
    Btl[(size_t)e * DD + k] = lo;
  }
}

// ------- Kernel C: sims = q @ kb^T via bf16 MFMA; threshold-compact survivors -------
// v3: 512 thr (8 waves, wave tile 32m x 64n). A-frags direct global->reg (q is L2-hot);
// B LDS-staged with 1-step register prefetch (named double-buffer). Bit-identical math.
__global__ __launch_bounds__(512) void k_sims_mfma(
    const unsigned short* __restrict__ qb, const float* __restrict__ kb,
    const float* __restrict__ tthr, int* __restrict__ gcnt,
    uint2* __restrict__ gcand) {
  __shared__ unsigned short Bs[64 * 32];   // 4 KB, swizzled
  __shared__ float sthr[256];
  int n0 = blockIdx.x * 64;
  int tid = threadIdx.x;
  int lane = tid & 63, w = tid >> 6;       // 8 waves
  int h = lane >> 4, c = lane & 15;
  if (tid < 256) sthr[tid] = tthr[tid];
  f32x4 acc[2][4] = {};
  const int brow = n0 + (tid >> 3);        // stage row (64 rows x 8 thr/row)
  const int bk4  = (tid & 7) * 4;          // 4 f32 per thread
  const int bwoff = ((tid >> 3) * 64 + (tid & 7) * 8) ^ (((tid >> 3) & 7) << 4);
  auto ldB = [&](int k0, float4 &dst) {
    dst = *(const float4*)(kb + (size_t)brow * DD + k0 + bk4);
  };
  auto stB = [&](const float4 &v) {
    uint2 p;
    p.x = (unsigned)f2bf_rne(v.x) | ((unsigned)f2bf_rne(v.y) << 16);
    p.y = (unsigned)f2bf_rne(v.z) | ((unsigned)f2bf_rne(v.w) << 16);
    *(uint2*)((char*)Bs + bwoff) = p;
  };
  const unsigned short* qa0 = qb + (size_t)(w * 32 + c) * DD;
  const unsigned short* qa1 = qb + (size_t)(w * 32 + 16 + c) * DD;
  auto step = [&](int k0, float4 &cur, float4 &nxt, bool pf) {
    bf16x8 a0 = *(const bf16x8*)(qa0 + k0 + h * 8);   // issue early (L2-hot)
    bf16x8 a1 = *(const bf16x8*)(qa1 + k0 + h * 8);
    __syncthreads();                 // prev MFMA done reading Bs
    stB(cur);
    if (pf) ldB(k0 + 32, nxt);       // prefetch next B under this step's MFMAs
    __syncthreads();                 // Bs ready
#pragma unroll
    for (int nf = 0; nf < 4; ++nf) {
      int n = nf * 16 + c;
      int off = (n * 64 + h * 16) ^ ((n & 7) << 4);
      bf16x8 b = *(bf16x8*)((char*)Bs + off);
      acc[0][nf] = __builtin_amdgcn_mfma_f32_16x16x32_bf16(a0, b, acc[0][nf], 0, 0, 0);
      acc[1][nf] = __builtin_amdgcn_mfma_f32_16x16x32_bf16(a1, b, acc[1][nf], 0, 0, 0);
    }
  };
  float4 b0, b1;
  ldB(0, b0);
#pragma unroll
  for (int kc = 0; kc < 12; ++kc) {
    step(kc * 64,      b0, b1, true);
    step(kc * 64 + 32, b1, b0, kc < 11);
  }
  // epilogue: C[row][col]: col = lane&15, row = (lane>>4)*4 + reg
#pragma unroll
  for (int mf = 0; mf < 2; ++mf)
#pragma unroll
    for (int nf = 0; nf < 4; ++nf)
#pragma unroll
      for (int r = 0; r < 4; ++r) {
        int row = w * 32 + mf * 16 + h * 4 + r;
        int col = n0 + nf * 16 + c;
        float v = acc[mf][nf][r];
        if (v > sthr[row]) {
          int p = atomicAdd(&gcnt[row], 1);
          if (p < SURV_CAP) gcand[(size_t)row * SURV_CAP + p] = make_uint2(__float_as_uint(v), (unsigned)col);
        }
      }
}

// ------- Kernel D: per-mention select top-200: sort survivors by f32 sims,
//         f64-rescore top RESC, exact sort, emit in sims-desc order -------
__global__ __launch_bounds__(256) void k_select(
    const uint2* __restrict__ gcand, const int* __restrict__ gcnt,
    const float* __restrict__ kb, const double* __restrict__ q64,
    int* __restrict__ cidx) {
  int m = blockIdx.x;
  __shared__ float skf[SURV_CAP];
  __shared__ int   sidx[SURV_CAP];
  __shared__ double sq[DD];
  __shared__ double skey[256];
  __shared__ int    skidx[256];
  int tid = threadIdx.x;
  int cnt = gcnt[m]; if (cnt > SURV_CAP) cnt = SURV_CAP;
  for (int d = tid; d < DD; d += 256) sq[d] = q64[(size_t)m * DD + d];
  for (int i = tid; i < SURV_CAP; i += 256) {
    if (i < cnt) {
      uint2 v = gcand[(size_t)m * SURV_CAP + i];
      skf[i] = __uint_as_float(v.x);
      sidx[i] = (int)v.y;
    } else { skf[i] = -FLT_MAX; sidx[i] = 0x7fffffff; }
  }
  __syncthreads();
  // bitonic sort 1024 desc by skf, tie -> smaller idx
  for (int k = 2; k <= SURV_CAP; k <<= 1) {
    for (int j = k >> 1; j > 0; j >>= 1) {
      for (int i = tid; i < SURV_CAP; i += 256) {
        int l = i ^ j;
        if (l > i) {
          float ka = skf[i], kb2 = skf[l];
          int ia = sidx[i], ib = sidx[l];
          bool lBefore = (kb2 > ka) || (kb2 == ka && ib < ia);
          bool iBefore = (ka > kb2) || (ka == kb2 && ia < ib);
          bool dir = ((i & k) == 0);
          bool sw = dir ? lBefore : iBefore;
          if (sw) { skf[i] = kb2; skf[l] = ka; sidx[i] = ib; sidx[l] = ia; }
        }
      }
      __syncthreads();
    }
  }
  // f64 rescore top RESC (one wave per candidate)
  int lane = tid & 63, wv = tid >> 6;
  for (int cpos = wv; cpos < RESC; cpos += 4) {
    int ci = sidx[cpos];
    double s;
    if (ci < NKB) {
      const float* krow = kb + (size_t)ci * DD;
      double acc = 0.0;
      for (int d = lane; d < DD; d += 64) acc += sq[d] * (double)krow[d];
      for (int off2 = 32; off2 > 0; off2 >>= 1) acc += __shfl_down(acc, off2, 64);
      s = acc;
    } else s = -INFINITY;
    if (lane == 0) { skey[cpos] = s; skidx[cpos] = ci; }
  }
  if (tid >= RESC && tid < 256) { skey[tid] = -INFINITY; skidx[tid] = 0x7fffffff; }
  __syncthreads();
  // bitonic sort 256 desc by f64 key, tie -> smaller idx
  for (int k = 2; k <= 256; k <<= 1) {
    for (int j = k >> 1; j > 0; j >>= 1) {
      int i = tid, l = i ^ j;
      if (l > i) {
        double ka = skey[i], kb2 = skey[l];
        int ia = skidx[i], ib = skidx[l];
        bool lBefore = (kb2 > ka) || (kb2 == ka && ib < ia);
        bool iBefore = (ka > kb2) || (ka == kb2 && ia < ib);
        bool dir = ((i & k) == 0);
        bool sw = dir ? lBefore : iBefore;
        if (sw) { skey[i] = kb2; skey[l] = ka; skidx[i] = ib; skidx[l] = ia; }
      }
      __syncthreads();
    }
  }
  for (int cc = tid; cc < KK; cc += 256) {
    int v = skidx[cc];
    cidx[(size_t)m * KK + cc] = (v < NKB) ? v : 0;
  }
}

// ------- Kernel E v4: scorer GEMM partials — R12 LDS-staged structure + T14 reg-prefetch.
// 256 thr (4 waves). Block = 256 cand rows x 64 e cols; K=768 in 32-k steps.
// Next step's A (8x float4, coalesced) and B (2x uint4) are loaded into registers
// BEFORE this step's MFMA section and written to LDS after the barrier.
// MFMA order per accumulator unchanged -> bit-identical z to R9-R12.
__global__ __launch_bounds__(256) void k_score2(
    const float* __restrict__ kb, const int* __restrict__ cidx,
    const float* __restrict__ mp32, const unsigned short* __restrict__ Bth,
    const unsigned short* __restrict__ Btl, const float* __restrict__ bs1,
    const float* __restrict__ Ws2, float* __restrict__ gpart) {
  __shared__ unsigned short Ah[256 * 32], Al[256 * 32];   // 16 KB each, swizzled
  __shared__ unsigned short Bh[64 * 32], Bl[64 * 32];     // 4 KB each, swizzled
  __shared__ float smp[3][64], sb1v[64], sw2v[64];
  __shared__ int srow[256];
  int p = blockIdx.x;
  int x = p & 7, j = p >> 3;
  int ct = x + 8 * (j / NET), et = j % NET;
  int r0 = ct * 256, e0 = et * 64;
  int tid = threadIdx.x, lane = tid & 63, w = tid >> 6;
  int h = lane >> 4, c = lane & 15;
  srow[tid] = cidx[r0 + tid];
  int m0 = r0 / KK;
  int mm1 = (m0 + 1 < MM) ? m0 + 1 : MM - 1;
  int mm2 = (m0 + 2 < MM) ? m0 + 2 : MM - 1;
  if (tid < 64) {
    smp[0][tid] = mp32[(size_t)m0 * DD + e0 + tid];
    smp[1][tid] = mp32[(size_t)mm1 * DD + e0 + tid];
    smp[2][tid] = mp32[(size_t)mm2 * DD + e0 + tid];
    sb1v[tid] = bs1[e0 + tid];
    sw2v[tid] = Ws2[e0 + tid];
  }
  __syncthreads();   // srow staged (needed for A addresses)
  // per-thread staging addresses (fixed across k): A rr = tid>>3 + it*32, f4 = tid&7
  const float* aaddr[8];
#pragma unroll
  for (int it = 0; it < 8; ++it) {
    int idx = tid + it * 256;
    int rr = idx >> 3, f4 = idx & 7;
    aaddr[it] = kb + (size_t)srow[rr] * DD + f4 * 4;
  }
  const int be = tid >> 2, bk8 = tid & 3;
  const unsigned short* bhaddr = Bth + (size_t)(e0 + be) * DD + bk8 * 8;
  const unsigned short* bladdr = Btl + (size_t)(e0 + be) * DD + bk8 * 8;
  // prefetch step 0
  float4 pa[8];
  uint4 pbh, pbl;
#pragma unroll
  for (int it = 0; it < 8; ++it) pa[it] = *(const float4*)(aaddr[it]);
  pbh = *(const uint4*)(bhaddr);
  pbl = *(const uint4*)(bladdr);
  f32x4 acc[4][4] = {};
  for (int k0 = 0; k0 < DD; k0 += 32) {
    __syncthreads();   // prev MFMA done reading LDS
    // write staged regs to LDS (split A here)
#pragma unroll
    for (int it = 0; it < 8; ++it) {
      int idx = tid + it * 256;
      int rr = idx >> 3, f4 = idx & 7;
      float4 v = pa[it];
      unsigned short h0, h1, h2, h3, l0, l1, l2, l3;
      splitbf(v.x, h0, l0); splitbf(v.y, h1, l1);
      splitbf(v.z, h2, l2); splitbf(v.w, h3, l3);
      uint2 ph, pl;
      ph.x = (unsigned)h0 | ((unsigned)h1 << 16); ph.y = (unsigned)h2 | ((unsigned)h3 << 16);
      pl.x = (unsigned)l0 | ((unsigned)l1 << 16); pl.y = (unsigned)l2 | ((unsigned)l3 << 16);
      int off = (rr * 64 + f4 * 8) ^ ((rr & 7) << 4);
      *(uint2*)((char*)Ah + off) = ph;
      *(uint2*)((char*)Al + off) = pl;
    }
    {
      int off = (be * 64 + bk8 * 16) ^ ((be & 7) << 4);
      *(uint4*)((char*)Bh + off) = pbh;
      *(uint4*)((char*)Bl + off) = pbl;
    }
    // issue next step's loads (hide under this step's MFMAs)
    if (k0 + 32 < DD) {
#pragma unroll
      for (int it = 0; it < 8; ++it) pa[it] = *(const float4*)(aaddr[it] + k0 + 32);
      pbh = *(const uint4*)(bhaddr + k0 + 32);
      pbl = *(const uint4*)(bladdr + k0 + 32);
    }
    __syncthreads();   // LDS ready
    bf16x8 ah[4], al[4];
#pragma unroll
    for (int mf = 0; mf < 4; ++mf) {
      int rr = w * 64 + mf * 16 + c;
      int off = (rr * 64 + h * 16) ^ ((rr & 7) << 4);
      ah[mf] = *(bf16x8*)((char*)Ah + off);
      al[mf] = *(bf16x8*)((char*)Al + off);
    }
#pragma unroll
    for (int nf = 0; nf < 4; ++nf) {
      int e = nf * 16 + c;
      int off = (e * 64 + h * 16) ^ ((e & 7) << 4);
      bf16x8 bh = *(bf16x8*)((char*)Bh + off);
      bf16x8 bl = *(bf16x8*)((char*)Bl + off);
#pragma unroll
      for (int mf = 0; mf < 4; ++mf) {
        acc[mf][nf] = __builtin_amdgcn_mfma_f32_16x16x32_bf16(ah[mf], bh, acc[mf][nf], 0, 0, 0);
        acc[mf][nf] = __builtin_amdgcn_mfma_f32_16x16x32_bf16(ah[mf], bl, acc[mf][nf], 0, 0, 0);
        acc[mf][nf] = __builtin_amdgcn_mfma_f32_16x16x32_bf16(al[mf], bh, acc[mf][nf], 0, 0, 0);
      }
    }
  }
  // epilogue: partial z over this 64-e tile; C/D: col=c -> e, row=h*4+r -> cand row
  int bnd1 = (m0 + 1) * KK, bnd2 = (m0 + 2) * KK;
#pragma unroll
  for (int mf = 0; mf < 4; ++mf) {
    float zp[4] = {0.f, 0.f, 0.f, 0.f};
#pragma unroll
    for (int nf = 0; nf < 4; ++nf) {
      int el = nf * 16 + c;
      float b1v = sb1v[el], w2v = sw2v[el];
#pragma unroll
      for (int r = 0; r < 4; ++r) {
        int rowg = r0 + w * 64 + mf * 16 + h * 4 + r;
        int sel = (rowg >= bnd1) + (rowg >= bnd2);
        float hh = acc[mf][nf][r] + smp[sel][el] + b1v;
        if (hh > 0.f) zp[r] += hh * w2v;
      }
    }
#pragma unroll
    for (int r = 0; r < 4; ++r) {
      float v = zp[r];
      v += __shfl_xor(v, 1, 64);
      v += __shfl_xor(v, 2, 64);
      v += __shfl_xor(v, 4, 64);
      v += __shfl_xor(v, 8, 64);
      if (c == 0)
        gpart[(size_t)(r0 + w * 64 + mf * 16 + h * 4 + r) * NET + et] = v;
    }
  }
}

// ------- Kernel E1b: z64[row] = f64 sum of 12 partials + bs2 (fixed order, deterministic) -------
__global__ __launch_bounds__(256) void k_zred(
    const float* __restrict__ gpart, const float* __restrict__ bs2,
    double* __restrict__ z64) {
  int r = blockIdx.x * 256 + threadIdx.x;
  double s = 0.0;
#pragma unroll
  for (int i = 0; i < NET; ++i) s += (double)gpart[(size_t)r * NET + i];
  z64[r] = s + (double)bs2[0];
}

// ------- Kernel E2: mark ambiguous ranks (any adjacent gap < DELTA), deduped -------
__global__ __launch_bounds__(256) void k_mark(
    const double* __restrict__ z64, int* __restrict__ marks, int* __restrict__ mcnt) {
  int m = blockIdx.x;
  __shared__ double sk[256];
  __shared__ int sp[256];
  __shared__ int flag[256];
  int tid = threadIdx.x;
  flag[tid] = 0;
  if (tid < KK) { sk[tid] = z64[(size_t)m * KK + tid]; sp[tid] = tid; }
  else { sk[tid] = -INFINITY; sp[tid] = 0x7fffffff; }
  __syncthreads();
  for (int k = 2; k <= 256; k <<= 1) {
    for (int j = k >> 1; j > 0; j >>= 1) {
      int i = tid, l = i ^ j;
      if (l > i) {
        double ka = sk[i], kb2 = sk[l];
        int ia = sp[i], ib = sp[l];
        bool lBefore = (kb2 > ka) || (kb2 == ka && ib < ia);
        bool iBefore = (ka > kb2) || (ka == kb2 && ia < ib);
        bool dir = ((i & k) == 0);
        bool sw = dir ? lBefore : iBefore;
        if (sw) { sk[i] = kb2; sk[l] = ka; sp[i] = ib; sp[l] = ia; }
      }
      __syncthreads();
    }
  }
  // mark rank positions involved in any close adjacent pair within ranks 0..121
  if (tid <= 120) {
    if (sk[tid] - sk[tid + 1] < DELTA) {
      flag[tid] = 1;
      atomicExch(&flag[tid + 1], 1);
    }
  }
  __syncthreads();
  if (tid <= 121 && flag[tid]) {
    int p = atomicAdd(mcnt, 1);
    if (p < MAXMARK) marks[p] = m * KK + sp[tid];
  }
}

// ------- Kernel E3: exact f64 rescore of marked candidates (in-place into z64) -------
__global__ __launch_bounds__(256) void k_rescore(
    const float* __restrict__ kb, const int* __restrict__ cidx,
    const double* __restrict__ mp64, const float* __restrict__ Ws1,
    const float* __restrict__ bs1, const float* __restrict__ Ws2,
    const float* __restrict__ bs2, const int* __restrict__ marks,
    const int* __restrict__ mcnt, double* __restrict__ z64) {
  int cnt = *mcnt; if (cnt > MAXMARK) cnt = MAXMARK;
  __shared__ float sc[DD];
  __shared__ double sred[256];
  int tid = threadIdx.x;
  for (int it = blockIdx.x; it < cnt; it += gridDim.x) {
    int r = marks[it];
    int m = r / KK;
    int row = cidx[r];
    for (int d = tid; d < DD; d += 256) sc[d] = kb[(size_t)row * DD + d];
    __syncthreads();
    double pz = 0.0;
    for (int e = tid; e < DD; e += 256) {
      double a = 0.0;
      for (int d = 0; d < DD; ++d) a += (double)sc[d] * (double)Ws1[(size_t)(DD + d) * DD + e];
      double hv = mp64[(size_t)m * DD + e] + a + (double)bs1[e];
      if (hv > 0) pz += hv * (double)Ws2[e];
    }
    sred[tid] = pz; __syncthreads();
    for (int s = 128; s > 0; s >>= 1) { if (tid < s) sred[tid] += sred[tid + s]; __syncthreads(); }
    if (tid == 0) z64[r] = sred[0] + (double)bs2[0];
    __syncthreads();
  }
}

// ---------------- Kernel F: per-mention top-100 of 200 (bitonic 256) ----------------
__global__ __launch_bounds__(256) void k_final(
    const double* __restrict__ z64, const int* __restrict__ cidx, float* __restrict__ out) {
  int m = blockIdx.x;
  __shared__ double sk[256];
  __shared__ int sp[256];
  int tid = threadIdx.x;
  if (tid < KK) { sk[tid] = z64[(size_t)m * KK + tid]; sp[tid] = tid; }
  else { sk[tid] = -INFINITY; sp[tid] = 0x7fffffff; }
  __syncthreads();
  for (int k = 2; k <= 256; k <<= 1) {
    for (int j = k >> 1; j > 0; j >>= 1) {
      int i = tid, l = i ^ j;
      if (l > i) {
        double ka = sk[i], kb2 = sk[l];
        int ia = sp[i], ib = sp[l];
        bool lBefore = (kb2 > ka) || (kb2 == ka && ib < ia);
        bool iBefore = (ka > kb2) || (ka == kb2 && ia < ib);
        bool dir = ((i & k) == 0);
        bool sw = dir ? lBefore : iBefore;
        if (sw) { sk[i] = kb2; sk[l] = ka; sp[i] = ib; sp[l] = ia; }
      }
      __syncthreads();
    }
  }
  if (tid < TOPK) {
    double z = sk[tid];
    out[(size_t)m * TOPK + tid] = (float)(1.0 / (1.0 + exp(-z)));
    out[(size_t)MM * TOPK + (size_t)m * TOPK + tid] = (float)cidx[(size_t)m * KK + sp[tid]];
  }
}

// ---------------- host ----------------
extern "C" void kernel_launch(void* const* d_in, const int* in_sizes, int n_in,
                              void* d_out, int out_size, void* d_ws, size_t ws_size,
                              hipStream_t stream) {
  const float* text  = (const float*)d_in[0];
  const float* kb    = (const float*)d_in[1];
  const float* Wret  = (const float*)d_in[2];
  const float* bret  = (const float*)d_in[3];
  const float* Ws1   = (const float*)d_in[4];
  const float* bs1   = (const float*)d_in[5];
  const float* Ws2   = (const float*)d_in[6];
  const float* bs2   = (const float*)d_in[7];
  const int* msent   = (const int*)d_in[8];
  const int* mstart  = (const int*)d_in[9];
  const int* mlen    = (const int*)d_in[10];
  float* out = (float*)d_out;

  char* ws = (char*)d_ws;
  size_t off = 0;
  auto alloc = [&](size_t bytes) -> void* {
    void* p = ws + off;
    off = (off + bytes + 255) & ~(size_t)255;
    return p;
  };
  double* me64 = (double*)alloc((size_t)MM * DD * 8);
  double* q64  = (double*)alloc((size_t)MM * DD * 8);
  unsigned short* qb16 = (unsigned short*)alloc((size_t)MM * DD * 2);
  float*  tthr = (float*) alloc((size_t)MM * 4);
  double* mp64 = (double*)alloc((size_t)MM * DD * 8);
  float*  mp32 = (float*) alloc((size_t)MM * DD * 4);
  int*    cidx = (int*)   alloc((size_t)MM * KK * 4);
  double* z64  = (double*)alloc((size_t)MM * KK * 8);
  float*  gpart = (float*)alloc((size_t)MM * KK * NET * 4);
  int*    marks = (int*)  alloc((size_t)MAXMARK * 4);
  int*    mcnt  = (int*)  alloc(256);
  int*    gcnt  = (int*)  alloc((size_t)MM * 4);
  uint2*  gcand = (uint2*)alloc((size_t)MM * SURV_CAP * 8);
  unsigned short* Bth = (unsigned short*)alloc((size_t)DD * DD * 2);
  unsigned short* Btl = (unsigned short*)alloc((size_t)DD * DD * 2);
  (void)ws_size;

  k_mention_emb<<<MM, 256, 0, stream>>>(text, msent, mstart, mlen, me64);
  k_query<<<MM, 256, 0, stream>>>(me64, Wret, bret, q64, qb16, tthr);
  k_mpart<<<MM, 256, 0, stream>>>(me64, Ws1, mp64, mp32);
  k_prep<<<DD, 256, 0, stream>>>(Ws1, Bth, Btl);

  hipMemsetAsync(gcnt, 0, (size_t)MM * 4, stream);
  k_sims_mfma<<<NKB / 64, 512, 0, stream>>>(qb16, kb, tthr, gcnt, gcand);
  k_select<<<MM, 256, 0, stream>>>(gcand, gcnt, kb, q64, cidx);

  k_score2<<<(MM * KK / 256) * NET, 256, 0, stream>>>(kb, cidx, mp32, Bth, Btl, bs1, Ws2, gpart);
  k_zred<<<MM * KK / 256, 256, 0, stream>>>(gpart, bs2, z64);
  hipMemsetAsync(mcnt, 0, 4, stream);
  k_mark<<<MM, 256, 0, stream>>>(z64, marks, mcnt);
  k_rescore<<<2048, 256, 0, stream>>>(kb, cidx, mp64, Ws1, bs1, Ws2, bs2, marks, mcnt, z64);
  k_final<<<MM, 256, 0, stream>>>(z64, cidx, out);
}

// Round 15
// 1305.052 us; speedup vs baseline: 1.1522x; 1.0239x over previous
//
#include <hip/hip_runtime.h>
#include <cfloat>
#include <cmath>
#include <cstdint>

#define DD 768
#define MM 256
#define NKB 200000
#define SLEN 512
#define KK 200      // 2*top_k
#define TOPK 100
#define SURV_CAP 1024
#define RESC 232
#define THRC 2.70f
#define MAXMARK 32768
#define DELTA 4e-5
#define NET 12      // e-tiles of 64

typedef __attribute__((ext_vector_type(8))) short bf16x8;
typedef __attribute__((ext_vector_type(4))) float f32x4;

__device__ __forceinline__ unsigned short f2bf_rne(float x) {
  unsigned u = __float_as_uint(x);
  unsigned r = (u + 0x7FFFu + ((u >> 16) & 1u)) >> 16;
  return (unsigned short)r;
}
__device__ __forceinline__ float bf2f(unsigned short us) {
  return __uint_as_float(((unsigned)us) << 16);
}
__device__ __forceinline__ void splitbf(float x, unsigned short& hi, unsigned short& lo) {
  hi = f2bf_rne(x);
  lo = f2bf_rne(x - bf2f(hi));
}

// ---------------- Kernel PT: WretT[d][e] = Wret[e][d] (LDS-tiled, coalesced both sides) ----------------
__global__ __launch_bounds__(256) void k_prepT(
    const float* __restrict__ Wret, float* __restrict__ WretT) {
  __shared__ float tile[64][65];
  int e0 = blockIdx.x * 64, d0 = blockIdx.y * 64;
  int tid = threadIdx.x;
  int r = tid >> 6, cc = tid & 63;
  for (int i = 0; i < 64; i += 4)
    tile[r + i][cc] = Wret[(size_t)(e0 + r + i) * DD + d0 + cc];
  __syncthreads();
  for (int i = 0; i < 64; i += 4)
    WretT[(size_t)(d0 + r + i) * DD + e0 + cc] = tile[cc][r + i];
}

// ------- Kernel FRONT: fused mention-mean + query (via WretT, coalesced) + m_part -------
// me lives only in LDS (f64); outputs: q64, qb16, tthr, mp64, mp32.
__global__ __launch_bounds__(256) void k_front(
    const float* __restrict__ text, const int* __restrict__ msent,
    const int* __restrict__ mstart, const int* __restrict__ mlen,
    const float* __restrict__ WretT, const float* __restrict__ bret,
    const float* __restrict__ Ws1,
    double* __restrict__ q64, unsigned short* __restrict__ qb16,
    float* __restrict__ tthr, double* __restrict__ mp64,
    float* __restrict__ mp32) {
  int m = blockIdx.x;
  __shared__ double sme[DD];
  __shared__ float snorm[256];
  int tid = threadIdx.x;
  {
    int sent = msent[m], st = mstart[m], ln = mlen[m];
    const float* base = text + (size_t)sent * SLEN * DD;
    for (int d = tid; d < DD; d += 256) {
      double acc = 0.0;
      for (int s = st; s <= st + ln; ++s) acc += (double)base[(size_t)s * DD + d];
      sme[d] = acc / (double)(ln + 1);
    }
  }
  __syncthreads();
  float nloc = 0.f;
  for (int e = tid; e < DD; e += 256) {
    double aq = (double)bret[e];
    double amp = 0.0;
    for (int d = 0; d < DD; ++d) {
      double md = sme[d];
      aq  += md * (double)WretT[(size_t)d * DD + e];
      amp += md * (double)Ws1[(size_t)d * DD + e];
    }
    q64[(size_t)m * DD + e] = aq;
    qb16[(size_t)m * DD + e] = f2bf_rne((float)aq);
    mp64[(size_t)m * DD + e] = amp;
    mp32[(size_t)m * DD + e] = (float)amp;
    nloc += (float)(aq * aq);
  }
  snorm[tid] = nloc; __syncthreads();
  for (int s = 128; s > 0; s >>= 1) {
    if (tid < s) snorm[tid] += snorm[tid + s];
    __syncthreads();
  }
  if (tid == 0) tthr[m] = THRC * sqrtf(snorm[0]);
}

// ---------------- Kernel P: split+transpose Ws1[D:] -> Bt_hi/Bt_lo [e][k] bf16 ----------------
__global__ __launch_bounds__(256) void k_prep(
    const float* __restrict__ Ws1, unsigned short* __restrict__ Bth,
    unsigned short* __restrict__ Btl) {
  int e = blockIdx.x;
  for (int k = threadIdx.x; k < DD; k += 256) {
    float x = Ws1[(size_t)(DD + k) * DD + e];
    unsigned short hi, lo;
    splitbf(x, hi, lo);
    Bth[(size_t)e * DD + k] = hi;
    Btl[(size_t)e * DD + k] = lo;
  }
}

// ------- Kernel C: sims = q @ kb^T via bf16 MFMA; threshold-compact survivors -------
// v3: 512 thr (8 waves, wave tile 32m x 64n). A-frags direct global->reg (q is L2-hot);
// B LDS-staged with 1-step register prefetch (named double-buffer).
__global__ __launch_bounds__(512) void k_sims_mfma(
    const unsigned short* __restrict__ qb, const float* __restrict__ kb,
    const float* __restrict__ tthr, int* __restrict__ gcnt,
    uint2* __restrict__ gcand) {
  __shared__ unsigned short Bs[64 * 32];   // 4 KB, swizzled
  __shared__ float sthr[256];
  int n0 = blockIdx.x * 64;
  int tid = threadIdx.x;
  int lane = tid & 63, w = tid >> 6;       // 8 waves
  int h = lane >> 4, c = lane & 15;
  if (tid < 256) sthr[tid] = tthr[tid];
  f32x4 acc[2][4] = {};
  const int brow = n0 + (tid >> 3);        // stage row (64 rows x 8 thr/row)
  const int bk4  = (tid & 7) * 4;          // 4 f32 per thread
  const int bwoff = ((tid >> 3) * 64 + (tid & 7) * 8) ^ (((tid >> 3) & 7) << 4);
  auto ldB = [&](int k0, float4 &dst) {
    dst = *(const float4*)(kb + (size_t)brow * DD + k0 + bk4);
  };
  auto stB = [&](const float4 &v) {
    uint2 p;
    p.x = (unsigned)f2bf_rne(v.x) | ((unsigned)f2bf_rne(v.y) << 16);
    p.y = (unsigned)f2bf_rne(v.z) | ((unsigned)f2bf_rne(v.w) << 16);
    *(uint2*)((char*)Bs + bwoff) = p;
  };
  const unsigned short* qa0 = qb + (size_t)(w * 32 + c) * DD;
  const unsigned short* qa1 = qb + (size_t)(w * 32 + 16 + c) * DD;
  auto step = [&](int k0, float4 &cur, float4 &nxt, bool pf) {
    bf16x8 a0 = *(const bf16x8*)(qa0 + k0 + h * 8);   // issue early (L2-hot)
    bf16x8 a1 = *(const bf16x8*)(qa1 + k0 + h * 8);
    __syncthreads();                 // prev MFMA done reading Bs
    stB(cur);
    if (pf) ldB(k0 + 32, nxt);       // prefetch next B under this step's MFMAs
    __syncthreads();                 // Bs ready
#pragma unroll
    for (int nf = 0; nf < 4; ++nf) {
      int n = nf * 16 + c;
      int off = (n * 64 + h * 16) ^ ((n & 7) << 4);
      bf16x8 b = *(bf16x8*)((char*)Bs + off);
      acc[0][nf] = __builtin_amdgcn_mfma_f32_16x16x32_bf16(a0, b, acc[0][nf], 0, 0, 0);
      acc[1][nf] = __builtin_amdgcn_mfma_f32_16x16x32_bf16(a1, b, acc[1][nf], 0, 0, 0);
    }
  };
  float4 b0, b1;
  ldB(0, b0);
#pragma unroll
  for (int kc = 0; kc < 12; ++kc) {
    step(kc * 64,      b0, b1, true);
    step(kc * 64 + 32, b1, b0, kc < 11);
  }
  // epilogue: C[row][col]: col = lane&15, row = (lane>>4)*4 + reg
#pragma unroll
  for (int mf = 0; mf < 2; ++mf)
#pragma unroll
    for (int nf = 0; nf < 4; ++nf)
#pragma unroll
      for (int r = 0; r < 4; ++r) {
        int row = w * 32 + mf * 16 + h * 4 + r;
        int col = n0 + nf * 16 + c;
        float v = acc[mf][nf][r];
        if (v > sthr[row]) {
          int p = atomicAdd(&gcnt[row], 1);
          if (p < SURV_CAP) gcand[(size_t)row * SURV_CAP + p] = make_uint2(__float_as_uint(v), (unsigned)col);
        }
      }
}

// ------- Kernel D: per-mention select top-200: sort survivors by f32 sims,
//         f64-rescore top RESC, exact sort, emit in sims-desc order -------
__global__ __launch_bounds__(256) void k_select(
    const uint2* __restrict__ gcand, const int* __restrict__ gcnt,
    const float* __restrict__ kb, const double* __restrict__ q64,
    int* __restrict__ cidx) {
  int m = blockIdx.x;
  __shared__ float skf[SURV_CAP];
  __shared__ int   sidx[SURV_CAP];
  __shared__ double sq[DD];
  __shared__ double skey[256];
  __shared__ int    skidx[256];
  int tid = threadIdx.x;
  int cnt = gcnt[m]; if (cnt > SURV_CAP) cnt = SURV_CAP;
  for (int d = tid; d < DD; d += 256) sq[d] = q64[(size_t)m * DD + d];
  for (int i = tid; i < SURV_CAP; i += 256) {
    if (i < cnt) {
      uint2 v = gcand[(size_t)m * SURV_CAP + i];
      skf[i] = __uint_as_float(v.x);
      sidx[i] = (int)v.y;
    } else { skf[i] = -FLT_MAX; sidx[i] = 0x7fffffff; }
  }
  __syncthreads();
  // bitonic sort 1024 desc by skf, tie -> smaller idx
  for (int k = 2; k <= SURV_CAP; k <<= 1) {
    for (int j = k >> 1; j > 0; j >>= 1) {
      for (int i = tid; i < SURV_CAP; i += 256) {
        int l = i ^ j;
        if (l > i) {
          float ka = skf[i], kb2 = skf[l];
          int ia = sidx[i], ib = sidx[l];
          bool lBefore = (kb2 > ka) || (kb2 == ka && ib < ia);
          bool iBefore = (ka > kb2) || (ka == kb2 && ia < ib);
          bool dir = ((i & k) == 0);
          bool sw = dir ? lBefore : iBefore;
          if (sw) { skf[i] = kb2; skf[l] = ka; sidx[i] = ib; sidx[l] = ia; }
        }
      }
      __syncthreads();
    }
  }
  // f64 rescore top RESC (one wave per candidate)
  int lane = tid & 63, wv = tid >> 6;
  for (int cpos = wv; cpos < RESC; cpos += 4) {
    int ci = sidx[cpos];
    double s;
    if (ci < NKB) {
      const float* krow = kb + (size_t)ci * DD;
      double acc = 0.0;
      for (int d = lane; d < DD; d += 64) acc += sq[d] * (double)krow[d];
      for (int off2 = 32; off2 > 0; off2 >>= 1) acc += __shfl_down(acc, off2, 64);
      s = acc;
    } else s = -INFINITY;
    if (lane == 0) { skey[cpos] = s; skidx[cpos] = ci; }
  }
  if (tid >= RESC && tid < 256) { skey[tid] = -INFINITY; skidx[tid] = 0x7fffffff; }
  __syncthreads();
  // bitonic sort 256 desc by f64 key, tie -> smaller idx
  for (int k = 2; k <= 256; k <<= 1) {
    for (int j = k >> 1; j > 0; j >>= 1) {
      int i = tid, l = i ^ j;
      if (l > i) {
        double ka = skey[i], kb2 = skey[l];
        int ia = skidx[i], ib = skidx[l];
        bool lBefore = (kb2 > ka) || (kb2 == ka && ib < ia);
        bool iBefore = (ka > kb2) || (ka == kb2 && ia < ib);
        bool dir = ((i & k) == 0);
        bool sw = dir ? lBefore : iBefore;
        if (sw) { skey[i] = kb2; skey[l] = ka; skidx[i] = ib; skidx[l] = ia; }
      }
      __syncthreads();
    }
  }
  for (int cc = tid; cc < KK; cc += 256) {
    int v = skidx[cc];
    cidx[(size_t)m * KK + cc] = (v < NKB) ? v : 0;
  }
}

// ------- Kernel E v4: scorer GEMM partials — LDS-staged + T14 reg-prefetch -------
__global__ __launch_bounds__(256) void k_score2(
    const float* __restrict__ kb, const int* __restrict__ cidx,
    const float* __restrict__ mp32, const unsigned short* __restrict__ Bth,
    const unsigned short* __restrict__ Btl, const float* __restrict__ bs1,
    const float* __restrict__ Ws2, float* __restrict__ gpart) {
  __shared__ unsigned short Ah[256 * 32], Al[256 * 32];   // 16 KB each, swizzled
  __shared__ unsigned short Bh[64 * 32], Bl[64 * 32];     // 4 KB each, swizzled
  __shared__ float smp[3][64], sb1v[64], sw2v[64];
  __shared__ int srow[256];
  int p = blockIdx.x;
  int x = p & 7, j = p >> 3;
  int ct = x + 8 * (j / NET), et = j % NET;
  int r0 = ct * 256, e0 = et * 64;
  int tid = threadIdx.x, lane = tid & 63, w = tid >> 6;
  int h = lane >> 4, c = lane & 15;
  srow[tid] = cidx[r0 + tid];
  int m0 = r0 / KK;
  int mm1 = (m0 + 1 < MM) ? m0 + 1 : MM - 1;
  int mm2 = (m0 + 2 < MM) ? m0 + 2 : MM - 1;
  if (tid < 64) {
    smp[0][tid] = mp32[(size_t)m0 * DD + e0 + tid];
    smp[1][tid] = mp32[(size_t)mm1 * DD + e0 + tid];
    smp[2][tid] = mp32[(size_t)mm2 * DD + e0 + tid];
    sb1v[tid] = bs1[e0 + tid];
    sw2v[tid] = Ws2[e0 + tid];
  }
  __syncthreads();   // srow staged (needed for A addresses)
  const float* aaddr[8];
#pragma unroll
  for (int it = 0; it < 8; ++it) {
    int idx = tid + it * 256;
    int rr = idx >> 3, f4 = idx & 7;
    aaddr[it] = kb + (size_t)srow[rr] * DD + f4 * 4;
  }
  const int be = tid >> 2, bk8 = tid & 3;
  const unsigned short* bhaddr = Bth + (size_t)(e0 + be) * DD + bk8 * 8;
  const unsigned short* bladdr = Btl + (size_t)(e0 + be) * DD + bk8 * 8;
  float4 pa[8];
  uint4 pbh, pbl;
#pragma unroll
  for (int it = 0; it < 8; ++it) pa[it] = *(const float4*)(aaddr[it]);
  pbh = *(const uint4*)(bhaddr);
  pbl = *(const uint4*)(bladdr);
  f32x4 acc[4][4] = {};
  for (int k0 = 0; k0 < DD; k0 += 32) {
    __syncthreads();   // prev MFMA done reading LDS
#pragma unroll
    for (int it = 0; it < 8; ++it) {
      int idx = tid + it * 256;
      int rr = idx >> 3, f4 = idx & 7;
      float4 v = pa[it];
      unsigned short h0, h1, h2, h3, l0, l1, l2, l3;
      splitbf(v.x, h0, l0); splitbf(v.y, h1, l1);
      splitbf(v.z, h2, l2); splitbf(v.w, h3, l3);
      uint2 ph, pl;
      ph.x = (unsigned)h0 | ((unsigned)h1 << 16); ph.y = (unsigned)h2 | ((unsigned)h3 << 16);
      pl.x = (unsigned)l0 | ((unsigned)l1 << 16); pl.y = (unsigned)l2 | ((unsigned)l3 << 16);
      int off = (rr * 64 + f4 * 8) ^ ((rr & 7) << 4);
      *(uint2*)((char*)Ah + off) = ph;
      *(uint2*)((char*)Al + off) = pl;
    }
    {
      int off = (be * 64 + bk8 * 16) ^ ((be & 7) << 4);
      *(uint4*)((char*)Bh + off) = pbh;
      *(uint4*)((char*)Bl + off) = pbl;
    }
    if (k0 + 32 < DD) {
#pragma unroll
      for (int it = 0; it < 8; ++it) pa[it] = *(const float4*)(aaddr[it] + k0 + 32);
      pbh = *(const uint4*)(bhaddr + k0 + 32);
      pbl = *(const uint4*)(bladdr + k0 + 32);
    }
    __syncthreads();   // LDS ready
    bf16x8 ah[4], al[4];
#pragma unroll
    for (int mf = 0; mf < 4; ++mf) {
      int rr = w * 64 + mf * 16 + c;
      int off = (rr * 64 + h * 16) ^ ((rr & 7) << 4);
      ah[mf] = *(bf16x8*)((char*)Ah + off);
      al[mf] = *(bf16x8*)((char*)Al + off);
    }
#pragma unroll
    for (int nf = 0; nf < 4; ++nf) {
      int e = nf * 16 + c;
      int off = (e * 64 + h * 16) ^ ((e & 7) << 4);
      bf16x8 bh = *(bf16x8*)((char*)Bh + off);
      bf16x8 bl = *(bf16x8*)((char*)Bl + off);
#pragma unroll
      for (int mf = 0; mf < 4; ++mf) {
        acc[mf][nf] = __builtin_amdgcn_mfma_f32_16x16x32_bf16(ah[mf], bh, acc[mf][nf], 0, 0, 0);
        acc[mf][nf] = __builtin_amdgcn_mfma_f32_16x16x32_bf16(ah[mf], bl, acc[mf][nf], 0, 0, 0);
        acc[mf][nf] = __builtin_amdgcn_mfma_f32_16x16x32_bf16(al[mf], bh, acc[mf][nf], 0, 0, 0);
      }
    }
  }
  int bnd1 = (m0 + 1) * KK, bnd2 = (m0 + 2) * KK;
#pragma unroll
  for (int mf = 0; mf < 4; ++mf) {
    float zp[4] = {0.f, 0.f, 0.f, 0.f};
#pragma unroll
    for (int nf = 0; nf < 4; ++nf) {
      int el = nf * 16 + c;
      float b1v = sb1v[el], w2v = sw2v[el];
#pragma unroll
      for (int r = 0; r < 4; ++r) {
        int rowg = r0 + w * 64 + mf * 16 + h * 4 + r;
        int sel = (rowg >= bnd1) + (rowg >= bnd2);
        float hh = acc[mf][nf][r] + smp[sel][el] + b1v;
        if (hh > 0.f) zp[r] += hh * w2v;
      }
    }
#pragma unroll
    for (int r = 0; r < 4; ++r) {
      float v = zp[r];
      v += __shfl_xor(v, 1, 64);
      v += __shfl_xor(v, 2, 64);
      v += __shfl_xor(v, 4, 64);
      v += __shfl_xor(v, 8, 64);
      if (c == 0)
        gpart[(size_t)(r0 + w * 64 + mf * 16 + h * 4 + r) * NET + et] = v;
    }
  }
}

// ------- Kernel E2: fused zred + mark (z = f64 sum of 12 partials + bs2; then sort, mark) -------
__global__ __launch_bounds__(256) void k_mark(
    const float* __restrict__ gpart, const float* __restrict__ bs2,
    double* __restrict__ z64, int* __restrict__ marks, int* __restrict__ mcnt) {
  int m = blockIdx.x;
  __shared__ double sk[256];
  __shared__ int sp[256];
  __shared__ int flag[256];
  int tid = threadIdx.x;
  flag[tid] = 0;
  if (tid < KK) {
    double s = 0.0;
#pragma unroll
    for (int i = 0; i < NET; ++i) s += (double)gpart[(size_t)(m * KK + tid) * NET + i];
    s += (double)bs2[0];
    z64[(size_t)m * KK + tid] = s;
    sk[tid] = s; sp[tid] = tid;
  } else { sk[tid] = -INFINITY; sp[tid] = 0x7fffffff; }
  __syncthreads();
  for (int k = 2; k <= 256; k <<= 1) {
    for (int j = k >> 1; j > 0; j >>= 1) {
      int i = tid, l = i ^ j;
      if (l > i) {
        double ka = sk[i], kb2 = sk[l];
        int ia = sp[i], ib = sp[l];
        bool lBefore = (kb2 > ka) || (kb2 == ka && ib < ia);
        bool iBefore = (ka > kb2) || (ka == kb2 && ia < ib);
        bool dir = ((i & k) == 0);
        bool sw = dir ? lBefore : iBefore;
        if (sw) { sk[i] = kb2; sk[l] = ka; sp[i] = ib; sp[l] = ia; }
      }
      __syncthreads();
    }
  }
  if (tid <= 120) {
    if (sk[tid] - sk[tid + 1] < DELTA) {
      flag[tid] = 1;
      atomicExch(&flag[tid + 1], 1);
    }
  }
  __syncthreads();
  if (tid <= 121 && flag[tid]) {
    int p = atomicAdd(mcnt, 1);
    if (p < MAXMARK) marks[p] = m * KK + sp[tid];
  }
}

// ------- Kernel E3: exact f64 rescore of marked candidates (in-place into z64) -------
__global__ __launch_bounds__(256) void k_rescore(
    const float* __restrict__ kb, const int* __restrict__ cidx,
    const double* __restrict__ mp64, const float* __restrict__ Ws1,
    const float* __restrict__ bs1, const float* __restrict__ Ws2,
    const float* __restrict__ bs2, const int* __restrict__ marks,
    const int* __restrict__ mcnt, double* __restrict__ z64) {
  int cnt = *mcnt; if (cnt > MAXMARK) cnt = MAXMARK;
  __shared__ float sc[DD];
  __shared__ double sred[256];
  int tid = threadIdx.x;
  for (int it = blockIdx.x; it < cnt; it += gridDim.x) {
    int r = marks[it];
    int m = r / KK;
    int row = cidx[r];
    for (int d = tid; d < DD; d += 256) sc[d] = kb[(size_t)row * DD + d];
    __syncthreads();
    double pz = 0.0;
    for (int e = tid; e < DD; e += 256) {
      double a = 0.0;
      for (int d = 0; d < DD; ++d) a += (double)sc[d] * (double)Ws1[(size_t)(DD + d) * DD + e];
      double hv = mp64[(size_t)m * DD + e] + a + (double)bs1[e];
      if (hv > 0) pz += hv * (double)Ws2[e];
    }
    sred[tid] = pz; __syncthreads();
    for (int s = 128; s > 0; s >>= 1) { if (tid < s) sred[tid] += sred[tid + s]; __syncthreads(); }
    if (tid == 0) z64[r] = sred[0] + (double)bs2[0];
    __syncthreads();
  }
}

// ---------------- Kernel F: per-mention top-100 of 200 (bitonic 256) ----------------
__global__ __launch_bounds__(256) void k_final(
    const double* __restrict__ z64, const int* __restrict__ cidx, float* __restrict__ out) {
  int m = blockIdx.x;
  __shared__ double sk[256];
  __shared__ int sp[256];
  int tid = threadIdx.x;
  if (tid < KK) { sk[tid] = z64[(size_t)m * KK + tid]; sp[tid] = tid; }
  else { sk[tid] = -INFINITY; sp[tid] = 0x7fffffff; }
  __syncthreads();
  for (int k = 2; k <= 256; k <<= 1) {
    for (int j = k >> 1; j > 0; j >>= 1) {
      int i = tid, l = i ^ j;
      if (l > i) {
        double ka = sk[i], kb2 = sk[l];
        int ia = sp[i], ib = sp[l];
        bool lBefore = (kb2 > ka) || (kb2 == ka && ib < ia);
        bool iBefore = (ka > kb2) || (ka == kb2 && ia < ib);
        bool dir = ((i & k) == 0);
        bool sw = dir ? lBefore : iBefore;
        if (sw) { sk[i] = kb2; sk[l] = ka; sp[i] = ib; sp[l] = ia; }
      }
      __syncthreads();
    }
  }
  if (tid < TOPK) {
    double z = sk[tid];
    out[(size_t)m * TOPK + tid] = (float)(1.0 / (1.0 + exp(-z)));
    out[(size_t)MM * TOPK + (size_t)m * TOPK + tid] = (float)cidx[(size_t)m * KK + sp[tid]];
  }
}

// ---------------- host ----------------
extern "C" void kernel_launch(void* const* d_in, const int* in_sizes, int n_in,
                              void* d_out, int out_size, void* d_ws, size_t ws_size,
                              hipStream_t stream) {
  const float* text  = (const float*)d_in[0];
  const float* kb    = (const float*)d_in[1];
  const float* Wret  = (const float*)d_in[2];
  const float* bret  = (const float*)d_in[3];
  const float* Ws1   = (const float*)d_in[4];
  const float* bs1   = (const float*)d_in[5];
  const float* Ws2   = (const float*)d_in[6];
  const float* bs2   = (const float*)d_in[7];
  const int* msent   = (const int*)d_in[8];
  const int* mstart  = (const int*)d_in[9];
  const int* mlen    = (const int*)d_in[10];
  float* out = (float*)d_out;

  char* ws = (char*)d_ws;
  size_t off = 0;
  auto alloc = [&](size_t bytes) -> void* {
    void* p = ws + off;
    off = (off + bytes + 255) & ~(size_t)255;
    return p;
  };
  double* q64  = (double*)alloc((size_t)MM * DD * 8);
  unsigned short* qb16 = (unsigned short*)alloc((size_t)MM * DD * 2);
  float*  tthr = (float*) alloc((size_t)MM * 4);
  double* mp64 = (double*)alloc((size_t)MM * DD * 8);
  float*  mp32 = (float*) alloc((size_t)MM * DD * 4);
  int*    cidx = (int*)   alloc((size_t)MM * KK * 4);
  double* z64  = (double*)alloc((size_t)MM * KK * 8);
  float*  gpart = (float*)alloc((size_t)MM * KK * NET * 4);
  int*    marks = (int*)  alloc((size_t)MAXMARK * 4);
  int*    mcnt  = (int*)  alloc(256);
  int*    gcnt  = (int*)  alloc((size_t)MM * 4);
  uint2*  gcand = (uint2*)alloc((size_t)MM * SURV_CAP * 8);
  unsigned short* Bth = (unsigned short*)alloc((size_t)DD * DD * 2);
  unsigned short* Btl = (unsigned short*)alloc((size_t)DD * DD * 2);
  float*  WretT = (float*)alloc((size_t)DD * DD * 4);
  (void)ws_size;

  dim3 gt(DD / 64, DD / 64);
  k_prepT<<<gt, 256, 0, stream>>>(Wret, WretT);
  k_prep<<<DD, 256, 0, stream>>>(Ws1, Bth, Btl);
  k_front<<<MM, 256, 0, stream>>>(text, msent, mstart, mlen, WretT, bret, Ws1,
                                  q64, qb16, tthr, mp64, mp32);

  hipMemsetAsync(gcnt, 0, (size_t)MM * 4, stream);
  k_sims_mfma<<<NKB / 64, 512, 0, stream>>>(qb16, kb, tthr, gcnt, gcand);
  k_select<<<MM, 256, 0, stream>>>(gcand, gcnt, kb, q64, cidx);

  k_score2<<<(MM * KK / 256) * NET, 256, 0, stream>>>(kb, cidx, mp32, Bth, Btl, bs1, Ws2, gpart);
  hipMemsetAsync(mcnt, 0, 4, stream);
  k_mark<<<MM, 256, 0, stream>>>(gpart, bs2, z64, marks, mcnt);
  k_rescore<<<2048, 256, 0, stream>>>(kb, cidx, mp64, Ws1, bs1, Ws2, bs2, marks, mcnt, z64);
  k_final<<<MM, 256, 0, stream>>>(z64, cidx, out);
}